// Round 1
// baseline (192.922 us; speedup 1.0000x reference)
//
#include <hip/hip_runtime.h>
#include <math.h>

// Kernel 1: vectorized copy lprobs -> out. out_size is divisible by 4 here
// (512*50257 = 25,731,584), but we handle a scalar tail for safety.
__global__ void ngram_copy_kernel(const float4* __restrict__ in4,
                                  float4* __restrict__ out4,
                                  const float* __restrict__ in,
                                  float* __restrict__ out,
                                  long long n4, long long n_total) {
    long long i = (long long)blockIdx.x * blockDim.x + threadIdx.x;
    long long stride = (long long)gridDim.x * blockDim.x;
    for (; i < n4; i += stride) {
        out4[i] = in4[i];
    }
    // scalar tail (n_total % 4 elements) handled by thread 0 of block 0
    if (blockIdx.x == 0 && threadIdx.x == 0) {
        for (long long t = n4 * 4; t < n_total; ++t) out[t] = in[t];
    }
}

// Kernel 2: scan windows, write -inf at banned tokens. Runs after copy on the
// same stream. Scalars live in device memory (graph capture forbids sync
// reads on host), so R/S/V are derived on-device from flat element counts.
__global__ void ngram_ban_kernel(const int* __restrict__ tokens,
                                 float* __restrict__ out,
                                 const int* __restrict__ bsz_p,
                                 const int* __restrict__ step_p,
                                 const int* __restrict__ beam_p,
                                 const int* __restrict__ n_p,
                                 long long tok_elems, long long lp_elems) {
    const int bsz  = *bsz_p;
    const int step = *step_p;
    const int beam = *beam_p;
    const int n    = *n_p;

    const int R = bsz * beam;
    const long long S = tok_elems / R;
    const long long V = lp_elems / R;
    const int num_windows = step - n + 2;
    const int last_start = step - n + 2;   // trailing (n-1)-gram begins here
    const int L = n - 1;

    for (int r = blockIdx.x; r < R; r += gridDim.x) {
        const int* __restrict__ trow = tokens + (long long)r * S;
        for (int j = threadIdx.x; j < num_windows; j += blockDim.x) {
            bool m = true;
            #pragma unroll 4
            for (int k = 0; k < L; ++k) {
                m &= (trow[j + k] == trow[last_start + k]);
            }
            if (m) {
                int banned = trow[j + n - 1];
                out[(long long)r * V + banned] = -INFINITY;
            }
        }
    }
}

extern "C" void kernel_launch(void* const* d_in, const int* in_sizes, int n_in,
                              void* d_out, int out_size, void* d_ws, size_t ws_size,
                              hipStream_t stream) {
    const int*   tokens = (const int*)d_in[0];
    const float* lprobs = (const float*)d_in[1];
    const int*   bsz_p  = (const int*)d_in[2];
    const int*   step_p = (const int*)d_in[3];
    const int*   beam_p = (const int*)d_in[4];
    const int*   n_p    = (const int*)d_in[5];
    float* out = (float*)d_out;

    const long long n_total = (long long)out_size;
    const long long n4 = n_total / 4;

    // 1) copy lprobs -> out
    {
        const int block = 256;
        long long blocks = (n4 + block - 1) / block;
        if (blocks < 1) blocks = 1;
        if (blocks > 1048576) blocks = 1048576;
        ngram_copy_kernel<<<(int)blocks, block, 0, stream>>>(
            (const float4*)lprobs, (float4*)out, lprobs, out, n4, n_total);
    }

    // 2) scatter -inf at banned positions (after copy completes on stream)
    {
        const int block = 256;
        const int blocks = 1024;  // >= R (512); device loop handles any R
        ngram_ban_kernel<<<blocks, block, 0, stream>>>(
            tokens, out, bsz_p, step_p, beam_p, n_p,
            (long long)in_sizes[0], (long long)in_sizes[1]);
    }
}